// Round 5
// baseline (262.148 us; speedup 1.0000x reference)
//
#include <hip/hip_runtime.h>

#define EMB 128

// ---------- per-row symmetric int8 quantization of the item table ----------
// One wave per row: lane reads 2 floats, wave-max via shfl, writes char2 + scale.
__global__ __launch_bounds__(256) void quant_kernel(
    const float* __restrict__ src, char* __restrict__ dst,
    float* __restrict__ scales, int n_rows)
{
    int w    = (blockIdx.x * 256 + threadIdx.x) >> 6;
    int lane = threadIdx.x & 63;
    if (w >= n_rows) return;
    float2 v = *(const float2*)(src + (size_t)w * EMB + lane * 2);
    float m = fmaxf(fabsf(v.x), fabsf(v.y));
    #pragma unroll
    for (int d = 1; d < 64; d <<= 1) m = fmaxf(m, __shfl_xor(m, d, 64));
    float inv = (m > 0.f) ? (127.f / m) : 0.f;
    char2 q;
    q.x = (char)__float2int_rn(v.x * inv);
    q.y = (char)__float2int_rn(v.y * inv);
    *(char2*)(dst + (size_t)w * EMB + lane * 2) = q;
    if (lane == 0) scales[w] = m * (1.f / 127.f);
}

// ---------- start[u] = first behavior with beh_user >= u (beh_user sorted) ----------
__global__ __launch_bounds__(256) void boundary_kernel(
    const int* __restrict__ beh_user, int* __restrict__ start,
    int n_beh, int n_users)
{
    int j = blockIdx.x * 256 + threadIdx.x;
    if (j >= n_beh) return;
    int cur  = beh_user[j];
    int prev = (j == 0) ? -1 : beh_user[j - 1];
    if (cur != prev) {
        for (int u = prev + 1; u <= cur; ++u) start[u] = j;
    }
    if (j == n_beh - 1) {
        for (int u = cur + 1; u <= n_users; ++u) start[u] = n_beh;
    }
}

// One wave per user. Row = 128 int8 = 128 B; 32 lanes per row, lane owns
// 4 dims (one dword). Lane-half 0 handles behaviors [j, j+8), half 1
// [j+8, j+16): one wave-load fetches TWO rows; unroll 8 => 16 rows in flight.
// Dequant: c_eff = cnt * scale[item]; halves merged via shfl_xor(32).
__global__ __launch_bounds__(256) void per_user_kernel(
    const int*   __restrict__ user_ids,
    const int*   __restrict__ group_ids,
    const int*   __restrict__ beh_item,
    const float* __restrict__ beh_cnt,
    const float* __restrict__ user_table,
    const char*  __restrict__ item_i8,
    const float* __restrict__ scales,
    const int*   __restrict__ start,
    float*       __restrict__ out,
    int n_users)
{
    const int lane = threadIdx.x & 63;
    const int half = lane >> 5;   // 0 or 1
    const int sub  = lane & 31;   // owns dims [sub*4, sub*4+4)
    const int wave = threadIdx.x >> 6;
    const int user = blockIdx.x * 4 + wave;

    __shared__ float lds_acc[EMB];
    __shared__ int   lds_grp[4];
    if (threadIdx.x < EMB) lds_acc[threadIdx.x] = 0.0f;

    float4 acc = make_float4(0.f, 0.f, 0.f, 0.f);
    int g = -1;

    if (user < n_users) {
        const int s = start[user];
        const int e = start[user + 1];

        const char* itp = item_i8 + sub * 4;   // this lane's dword slice

        int j = s;
        for (; j + 16 <= e; j += 16) {
            const int base = j + half * 8;
            int   bidx[8];
            float bcnt[8];
            #pragma unroll
            for (int k = 0; k < 8; ++k) { bidx[k] = beh_item[base + k]; bcnt[k] = beh_cnt[base + k]; }
            unsigned raw[8];
            #pragma unroll
            for (int k = 0; k < 8; ++k)
                raw[k] = *(const unsigned*)(itp + (size_t)bidx[k] * EMB);
            float sc[8];
            #pragma unroll
            for (int k = 0; k < 8; ++k) sc[k] = scales[bidx[k]];
            #pragma unroll
            for (int k = 0; k < 8; ++k) {
                float c = bcnt[k] * sc[k];
                float f0 = (float)(int)(char)(raw[k]);
                float f1 = (float)(int)(char)(raw[k] >> 8);
                float f2 = (float)(int)(char)(raw[k] >> 16);
                float f3 = (float)(int)(raw[k] >> 24 << 24 >> 24);  // sign-extend top byte
                f3 = (float)(int)(char)(raw[k] >> 24);
                acc.x = fmaf(f0, c, acc.x);
                acc.y = fmaf(f1, c, acc.y);
                acc.z = fmaf(f2, c, acc.z);
                acc.w = fmaf(f3, c, acc.w);
            }
        }
        // tail: 2 behaviors per iteration (half h takes j+h), masked
        for (; j < e; j += 2) {
            int   jj = j + half;
            int   bi = 0;
            float c  = 0.f;
            if (jj < e) { bi = beh_item[jj]; c = beh_cnt[jj] * scales[bi]; }
            unsigned raw = *(const unsigned*)(itp + (size_t)bi * EMB);
            float f0 = (float)(int)(char)(raw);
            float f1 = (float)(int)(char)(raw >> 8);
            float f2 = (float)(int)(char)(raw >> 16);
            float f3 = (float)(int)(char)(raw >> 24);
            acc.x = fmaf(f0, c, acc.x);
            acc.y = fmaf(f1, c, acc.y);
            acc.z = fmaf(f2, c, acc.z);
            acc.w = fmaf(f3, c, acc.w);
        }

        // combine halves (lanes L and L^32 hold partials of the same dims)
        acc.x += __shfl_xor(acc.x, 32, 64);
        acc.y += __shfl_xor(acc.y, 32, 64);
        acc.z += __shfl_xor(acc.z, 32, 64);
        acc.w += __shfl_xor(acc.w, 32, 64);

        int uid = user_ids[user];
        float4 ue = make_float4(0.f, 0.f, 0.f, 0.f);
        if (uid != 0) ue = *(const float4*)(user_table + (size_t)uid * EMB + sub * 4);
        acc.x *= ue.x; acc.y *= ue.y; acc.z *= ue.z; acc.w *= ue.w;

        g = group_ids[user];
    }

    // lane<32 writes dims sub*4+{0,1}; lane>=32 writes sub*4+{2,3}
    const int   d0 = sub * 4 + half * 2;
    const float v0 = half ? acc.z : acc.x;
    const float v1 = half ? acc.w : acc.y;

    if (lane == 0) lds_grp[wave] = g;
    __syncthreads();

    int g0 = lds_grp[0];
    bool same = (g0 >= 0) && (lds_grp[1] == g0) && (lds_grp[2] == g0) && (lds_grp[3] == g0);
    if (same) {
        atomicAdd(&lds_acc[d0],     v0);
        atomicAdd(&lds_acc[d0 + 1], v1);
        __syncthreads();
        if (wave == 0) {
            atomicAdd(&out[(size_t)g0 * EMB + d0],     lds_acc[d0]);
            atomicAdd(&out[(size_t)g0 * EMB + d0 + 1], lds_acc[d0 + 1]);
        }
    } else if (g >= 0) {
        atomicAdd(&out[(size_t)g * EMB + d0],     v0);
        atomicAdd(&out[(size_t)g * EMB + d0 + 1], v1);
    }
}

// ---------- fp32 fallback (ws too small) ----------
__global__ __launch_bounds__(256) void per_user_f32_kernel(
    const int*   __restrict__ user_ids,
    const int*   __restrict__ group_ids,
    const int*   __restrict__ beh_item,
    const float* __restrict__ beh_cnt,
    const int*   __restrict__ beh_user,
    const float* __restrict__ user_table,
    const float* __restrict__ item_f32,
    float*       __restrict__ out,
    int n_users, int n_beh)
{
    const int lane = threadIdx.x & 63;
    const int wave = threadIdx.x >> 6;
    const int user = blockIdx.x * 4 + wave;
    float2 acc = make_float2(0.f, 0.f);
    int g = -1;
    if (user < n_users) {
        int lo = 0, hi = n_beh;
        while (lo < hi) { int m = (lo + hi) >> 1; if (beh_user[m] < user) lo = m + 1; else hi = m; }
        int s = lo; hi = n_beh;
        while (lo < hi) { int m = (lo + hi) >> 1; if (beh_user[m] <= user) lo = m + 1; else hi = m; }
        int e = lo;
        for (int j = s; j < e; ++j) {
            int   b = beh_item[j];
            float c = beh_cnt[j];
            float2 v = *(const float2*)(item_f32 + (size_t)b * EMB + lane * 2);
            acc.x = fmaf(v.x, c, acc.x);
            acc.y = fmaf(v.y, c, acc.y);
        }
        int uid = user_ids[user];
        float2 ue = make_float2(0.f, 0.f);
        if (uid != 0) ue = *(const float2*)(user_table + (size_t)uid * EMB + lane * 2);
        acc.x *= ue.x; acc.y *= ue.y;
        g = group_ids[user];
    }
    if (g >= 0) {
        atomicAdd(&out[(size_t)g * EMB + lane * 2],     acc.x);
        atomicAdd(&out[(size_t)g * EMB + lane * 2 + 1], acc.y);
    }
}

extern "C" void kernel_launch(void* const* d_in, const int* in_sizes, int n_in,
                              void* d_out, int out_size, void* d_ws, size_t ws_size,
                              hipStream_t stream) {
    const int*   user_ids   = (const int*)  d_in[0];
    const int*   group_ids  = (const int*)  d_in[1];
    const int*   beh_item   = (const int*)  d_in[2];
    const float* beh_cnt    = (const float*)d_in[3];
    const int*   beh_user   = (const int*)  d_in[4];
    const float* user_table = (const float*)d_in[5];
    const float* item_table = (const float*)d_in[6];

    const int n_users = in_sizes[0];
    const int n_beh   = in_sizes[2];
    const int item_n  = in_sizes[6] / EMB;

    float* out = (float*)d_out;
    hipMemsetAsync(out, 0, (size_t)out_size * sizeof(float), stream);

    // ws layout: start | scales | item_i8  (256B aligned)
    size_t off = 0;
    auto take = [&](size_t bytes) { size_t o = off; off = (off + bytes + 255) & ~(size_t)255; return o; };
    size_t o_start = take((size_t)(n_users + 1) * sizeof(int));
    size_t o_scale = take((size_t)item_n * sizeof(float));
    size_t o_i8    = take((size_t)item_n * EMB);

    if (off > ws_size) {
        int ublocks = (n_users + 3) / 4;
        per_user_f32_kernel<<<ublocks, 256, 0, stream>>>(
            user_ids, group_ids, beh_item, beh_cnt, beh_user,
            user_table, item_table, out, n_users, n_beh);
        return;
    }

    int*   start   = (int*)  ((char*)d_ws + o_start);
    float* scales  = (float*)((char*)d_ws + o_scale);
    char*  item_i8 = (char*) ((char*)d_ws + o_i8);

    boundary_kernel<<<(n_beh + 255) / 256, 256, 0, stream>>>(beh_user, start, n_beh, n_users);

    quant_kernel<<<(item_n + 3) / 4, 256, 0, stream>>>(item_table, item_i8, scales, item_n);

    int ublocks = (n_users + 3) / 4;
    per_user_kernel<<<ublocks, 256, 0, stream>>>(
        user_ids, group_ids, beh_item, beh_cnt,
        user_table, item_i8, scales, start, out, n_users);
}

// Round 6
// 249.732 us; speedup vs baseline: 1.0497x; 1.0497x over previous
//
#include <hip/hip_runtime.h>
#include <hip/hip_fp16.h>

#define EMB 128

// ---------- fp32 -> fp16 item table ----------
__global__ __launch_bounds__(256) void convert_kernel(
    const float* __restrict__ src, __half* __restrict__ dst, int n8)
{
    int t = blockIdx.x * 256 + threadIdx.x;
    if (t >= n8) return;
    const float4* s = (const float4*)src + (size_t)t * 2;
    float4 f0 = s[0];
    float4 f1 = s[1];
    union { __half h[8]; uint4 u; } pk;
    pk.h[0] = __float2half_rn(f0.x); pk.h[1] = __float2half_rn(f0.y);
    pk.h[2] = __float2half_rn(f0.z); pk.h[3] = __float2half_rn(f0.w);
    pk.h[4] = __float2half_rn(f1.x); pk.h[5] = __float2half_rn(f1.y);
    pk.h[6] = __float2half_rn(f1.z); pk.h[7] = __float2half_rn(f1.w);
    ((uint4*)dst)[t] = pk.u;
}

// ---------- boundary + (item,cnt) pair packing, one pass ----------
// start[u] = first behavior with beh_user >= u (beh_user sorted).
// pairs[j] = (item_id, cnt bits)  -> one 8B load serves both in the hot loop.
__global__ __launch_bounds__(256) void prep_kernel(
    const int*   __restrict__ beh_user,
    const int*   __restrict__ beh_item,
    const float* __restrict__ beh_cnt,
    int*  __restrict__ start,
    int2* __restrict__ pairs,
    int n_beh, int n_users)
{
    int j = blockIdx.x * 256 + threadIdx.x;
    if (j >= n_beh) return;
    pairs[j] = make_int2(beh_item[j], __float_as_int(beh_cnt[j]));
    int cur  = beh_user[j];
    int prev = (j == 0) ? -1 : beh_user[j - 1];
    if (cur != prev) {
        for (int u = prev + 1; u <= cur; ++u) start[u] = j;
    }
    if (j == n_beh - 1) {
        for (int u = cur + 1; u <= n_users; ++u) start[u] = n_beh;
    }
}

// One wave per user. Row = 128 fp16 = 256 B; 16 lanes per row, lane owns
// 8 dims (uint4 = 16 B, the coalescing sweet spot). Quarter q (lanes
// 16q..16q+15) handles behaviors j+4q..j+4q+3 -> one load instruction
// fetches FOUR rows; unroll 4 => 16 rows in flight per wave.
// Quarter partials merged via shfl_xor(16) + shfl_xor(32).
__global__ __launch_bounds__(256) void per_user_kernel(
    const int*    __restrict__ user_ids,
    const int*    __restrict__ group_ids,
    const int2*   __restrict__ pairs,
    const float*  __restrict__ user_table,
    const __half* __restrict__ item_f16,
    const int*    __restrict__ start,
    float*        __restrict__ out,
    int n_users)
{
    const int lane = threadIdx.x & 63;
    const int q    = lane >> 4;    // quarter 0..3
    const int s16  = lane & 15;    // owns dims [s16*8, s16*8+8)
    const int wave = threadIdx.x >> 6;
    const int user = blockIdx.x * 4 + wave;

    __shared__ float lds_acc[EMB];
    __shared__ int   lds_grp[4];
    if (threadIdx.x < EMB) lds_acc[threadIdx.x] = 0.0f;

    float acc[8] = {0.f, 0.f, 0.f, 0.f, 0.f, 0.f, 0.f, 0.f};
    int g = -1;

    if (user < n_users) {
        const int s = start[user];
        const int e = start[user + 1];

        const __half* itp = item_f16 + s16 * 8;   // this lane's 16B slice

        int j = s;
        for (; j + 16 <= e; j += 16) {
            int2 p[4];
            #pragma unroll
            for (int k = 0; k < 4; ++k) p[k] = pairs[j + q * 4 + k];
            uint4 raw[4];
            #pragma unroll
            for (int k = 0; k < 4; ++k)
                raw[k] = *(const uint4*)(itp + (size_t)p[k].x * EMB);
            #pragma unroll
            for (int k = 0; k < 4; ++k) {
                float c = __int_as_float(p[k].y);
                const __half2* h = (const __half2*)&raw[k];
                #pragma unroll
                for (int d = 0; d < 4; ++d) {
                    float2 f = __half22float2(h[d]);
                    acc[d * 2]     = fmaf(f.x, c, acc[d * 2]);
                    acc[d * 2 + 1] = fmaf(f.y, c, acc[d * 2 + 1]);
                }
            }
        }
        // tail: 4 rows per iteration (quarter q takes j+q), masked via c=0
        for (; j < e; j += 4) {
            int jj = j + q;
            int2 p = make_int2(0, 0);
            if (jj < e) p = pairs[jj];
            float c = __int_as_float(p.y);
            uint4 raw = *(const uint4*)(itp + (size_t)p.x * EMB);
            const __half2* h = (const __half2*)&raw;
            #pragma unroll
            for (int d = 0; d < 4; ++d) {
                float2 f = __half22float2(h[d]);
                acc[d * 2]     = fmaf(f.x, c, acc[d * 2]);
                acc[d * 2 + 1] = fmaf(f.y, c, acc[d * 2 + 1]);
            }
        }

        // merge quarters: lanes sharing s16 sum their partials
        #pragma unroll
        for (int d = 0; d < 8; ++d) {
            acc[d] += __shfl_xor(acc[d], 16, 64);
            acc[d] += __shfl_xor(acc[d], 32, 64);
        }

        int uid = user_ids[user];
        float4 ue0 = make_float4(0.f, 0.f, 0.f, 0.f), ue1 = ue0;
        if (uid != 0) {
            const float* up = user_table + (size_t)uid * EMB + s16 * 8;
            ue0 = *(const float4*)(up);
            ue1 = *(const float4*)(up + 4);
        }
        acc[0] *= ue0.x; acc[1] *= ue0.y; acc[2] *= ue0.z; acc[3] *= ue0.w;
        acc[4] *= ue1.x; acc[5] *= ue1.y; acc[6] *= ue1.z; acc[7] *= ue1.w;

        g = group_ids[user];
    }

    if (lane == 0) lds_grp[wave] = g;
    __syncthreads();

    int g0 = lds_grp[0];
    bool same = (g0 >= 0) && (lds_grp[1] == g0) && (lds_grp[2] == g0) && (lds_grp[3] == g0);
    if (same) {
        if (q == 0) {   // 'same' implies all 4 users valid
            #pragma unroll
            for (int d = 0; d < 8; ++d) atomicAdd(&lds_acc[s16 * 8 + d], acc[d]);
        }
        __syncthreads();
        if (wave == 0) {
            atomicAdd(&out[(size_t)g0 * EMB + lane * 2],     lds_acc[lane * 2]);
            atomicAdd(&out[(size_t)g0 * EMB + lane * 2 + 1], lds_acc[lane * 2 + 1]);
        }
    } else if (g >= 0 && q == 0) {
        #pragma unroll
        for (int d = 0; d < 8; ++d)
            atomicAdd(&out[(size_t)g * EMB + s16 * 8 + d], acc[d]);
    }
}

// ---------- fp32 fallback (ws too small) ----------
__global__ __launch_bounds__(256) void per_user_f32_kernel(
    const int*   __restrict__ user_ids,
    const int*   __restrict__ group_ids,
    const int*   __restrict__ beh_item,
    const float* __restrict__ beh_cnt,
    const int*   __restrict__ beh_user,
    const float* __restrict__ user_table,
    const float* __restrict__ item_f32,
    float*       __restrict__ out,
    int n_users, int n_beh)
{
    const int lane = threadIdx.x & 63;
    const int wave = threadIdx.x >> 6;
    const int user = blockIdx.x * 4 + wave;
    float2 acc = make_float2(0.f, 0.f);
    int g = -1;
    if (user < n_users) {
        int lo = 0, hi = n_beh;
        while (lo < hi) { int m = (lo + hi) >> 1; if (beh_user[m] < user) lo = m + 1; else hi = m; }
        int s = lo; hi = n_beh;
        while (lo < hi) { int m = (lo + hi) >> 1; if (beh_user[m] <= user) lo = m + 1; else hi = m; }
        int e = lo;
        for (int j = s; j < e; ++j) {
            int   b = beh_item[j];
            float c = beh_cnt[j];
            float2 v = *(const float2*)(item_f32 + (size_t)b * EMB + lane * 2);
            acc.x = fmaf(v.x, c, acc.x);
            acc.y = fmaf(v.y, c, acc.y);
        }
        int uid = user_ids[user];
        float2 ue = make_float2(0.f, 0.f);
        if (uid != 0) ue = *(const float2*)(user_table + (size_t)uid * EMB + lane * 2);
        acc.x *= ue.x; acc.y *= ue.y;
        g = group_ids[user];
    }
    if (g >= 0) {
        atomicAdd(&out[(size_t)g * EMB + lane * 2],     acc.x);
        atomicAdd(&out[(size_t)g * EMB + lane * 2 + 1], acc.y);
    }
}

extern "C" void kernel_launch(void* const* d_in, const int* in_sizes, int n_in,
                              void* d_out, int out_size, void* d_ws, size_t ws_size,
                              hipStream_t stream) {
    const int*   user_ids   = (const int*)  d_in[0];
    const int*   group_ids  = (const int*)  d_in[1];
    const int*   beh_item   = (const int*)  d_in[2];
    const float* beh_cnt    = (const float*)d_in[3];
    const int*   beh_user   = (const int*)  d_in[4];
    const float* user_table = (const float*)d_in[5];
    const float* item_table = (const float*)d_in[6];

    const int n_users = in_sizes[0];
    const int n_beh   = in_sizes[2];
    const int item_n  = in_sizes[6] / EMB;

    float* out = (float*)d_out;
    hipMemsetAsync(out, 0, (size_t)out_size * sizeof(float), stream);

    // ws layout: start | pairs | item_f16  (256B aligned)
    size_t off = 0;
    auto take = [&](size_t bytes) { size_t o = off; off = (off + bytes + 255) & ~(size_t)255; return o; };
    size_t o_start = take((size_t)(n_users + 1) * sizeof(int));
    size_t o_pairs = take((size_t)n_beh * sizeof(int2));
    size_t o_f16   = take((size_t)item_n * EMB * sizeof(__half));

    if (off > ws_size) {
        int ublocks = (n_users + 3) / 4;
        per_user_f32_kernel<<<ublocks, 256, 0, stream>>>(
            user_ids, group_ids, beh_item, beh_cnt, beh_user,
            user_table, item_table, out, n_users, n_beh);
        return;
    }

    int*    start    = (int*)   ((char*)d_ws + o_start);
    int2*   pairs    = (int2*)  ((char*)d_ws + o_pairs);
    __half* item_f16 = (__half*)((char*)d_ws + o_f16);

    prep_kernel<<<(n_beh + 255) / 256, 256, 0, stream>>>(
        beh_user, beh_item, beh_cnt, start, pairs, n_beh, n_users);

    int n8 = (item_n * EMB) / 8;
    convert_kernel<<<(n8 + 255) / 256, 256, 0, stream>>>(item_table, item_f16, n8);

    int ublocks = (n_users + 3) / 4;
    per_user_kernel<<<ublocks, 256, 0, stream>>>(
        user_ids, group_ids, pairs, user_table, item_f16, start, out, n_users);
}